// Round 1
// baseline (21182.201 us; speedup 1.0000x reference)
//
#include <hip/hip_runtime.h>
#include <hip/hip_fp16.h>
#include <hip/hip_cooperative_groups.h>

namespace cg = cooperative_groups;

// LSTM: B=64, T=1024, I=256, H=512.
// Persistent weight-stationary design:
//   128 WGs x 256 threads (4 waves). WG g owns h-columns [4g, 4g+4) -> 16 gate
//   columns (f,i,c~,o x 4). Weight slice [768,16] f16 lives in VGPRs (24 MFMA
//   B-fragments), loaded once before the t-loop. Each step: every WG reads all
//   of h (f16, 64KB) + x_t (f32) from L2, does 24 mfma_f32_16x16x32_f16 per
//   wave, applies activations, updates its private c-slice (registers), writes
//   its 256 h values f16 to the double-buffered exchange buffer, grid.sync().
// One grid.sync per step is sufficient with double buffering: arrival at the
// barrier for step t implies that WG finished reading h_{t-1}, so overwriting
// h_{t-2}'s buffer at step t+1 is safe.

#define T_STEPS 1024
#define BATCH   64
#define ISZ     256
#define HSZ     512
#define NWG     128
#define NTHR    256

typedef _Float16 half8  __attribute__((ext_vector_type(8)));
typedef float    floatx4 __attribute__((ext_vector_type(4)));

__device__ __forceinline__ float fast_sigmoid(float x) {
    return 1.0f / (1.0f + __expf(-x));
}
__device__ __forceinline__ float fast_tanh(float x) {
    // 1 - 2/(e^{2x}+1); saturates gracefully at +-1 for large |x|
    return 1.0f - 2.0f / (__expf(2.0f * x) + 1.0f);
}

__global__ __launch_bounds__(NTHR, 1) void lstm_persist(
    const float* __restrict__ x,
    const float* __restrict__ Wf, const float* __restrict__ bfv,
    const float* __restrict__ Wi, const float* __restrict__ biv,
    const float* __restrict__ Wc, const float* __restrict__ bcv,
    const float* __restrict__ Wo, const float* __restrict__ bov,
    _Float16* __restrict__ hbuf)   // [2][64][512] f16 double buffer
{
    cg::grid_group grid = cg::this_grid();

    const int g    = blockIdx.x;        // 0..127
    const int tid  = threadIdx.x;       // 0..255
    const int w    = tid >> 6;          // wave 0..3  -> batch rows [16w,16w+16)
    const int l    = tid & 63;          // lane
    const int lj   = l & 15;            // MFMA col (B) / row (A) position
    const int lk   = l >> 4;            // k-group 0..3
    const int gate = lj >> 2;           // 0=f 1=i 2=c~ 3=o
    const int jc   = lj & 3;            // which of the 4 h-cols
    const int hc   = (g << 2) + jc;     // h column in [0,512)
    const int row0 = w << 4;            // batch base for this wave
    const int arow = row0 + lj;         // A-operand batch row for this lane

    const float* Wg = (gate == 0) ? Wf : (gate == 1) ? Wi : (gate == 2) ? Wc : Wo;
    const float* bg = (gate == 0) ? bfv : (gate == 1) ? biv : (gate == 2) ? bcv : bov;

    // ---- B fragments (weights) in registers, loaded once. K order within a
    // fragment is (lk*8 + e); A uses the identical mapping, so any HW k-layout
    // permutation cancels. W rows 0..255 = x part, 256..767 = h part.
    half8 Bfrag[24];
    #pragma unroll
    for (int kf = 0; kf < 24; ++kf) {
        half8 v;
        #pragma unroll
        for (int e = 0; e < 8; ++e) {
            int k = (kf << 5) + (lk << 3) + e;
            v[e] = (_Float16)Wg[(size_t)k * HSZ + hc];
        }
        Bfrag[kf] = v;
    }
    const float bias = bg[hc];

    float cst[4] = {0.f, 0.f, 0.f, 0.f};   // c-state, rows row0+lk*4+e (gate==0 lanes)

    const size_t HB = (size_t)BATCH * HSZ;

    for (int t = 0; t < T_STEPS; ++t) {
        const _Float16* hread  = hbuf + (size_t)(t & 1) * HB;
        _Float16*       hwrite = hbuf + (size_t)((t + 1) & 1) * HB;

        floatx4 acc = {bias, bias, bias, bias};

        // x part: K = 256 (8 fragments), read f32 and convert
        const float* xrow = x + ((size_t)arow * T_STEPS + t) * ISZ + (lk << 3);
        #pragma unroll
        for (int kf = 0; kf < 8; ++kf) {
            floatx4 x0 = *(const floatx4*)(xrow + (kf << 5));
            floatx4 x1 = *(const floatx4*)(xrow + (kf << 5) + 4);
            half8 a;
            a[0] = (_Float16)x0[0]; a[1] = (_Float16)x0[1];
            a[2] = (_Float16)x0[2]; a[3] = (_Float16)x0[3];
            a[4] = (_Float16)x1[0]; a[5] = (_Float16)x1[1];
            a[6] = (_Float16)x1[2]; a[7] = (_Float16)x1[3];
            acc = __builtin_amdgcn_mfma_f32_16x16x32_f16(a, Bfrag[kf], acc, 0, 0, 0);
        }
        // h part: K = 512 (16 fragments), f16 direct
        const _Float16* hrow = hread + (size_t)arow * HSZ + (lk << 3);
        #pragma unroll
        for (int kf = 0; kf < 16; ++kf) {
            half8 a = *(const half8*)(hrow + (kf << 5));
            acc = __builtin_amdgcn_mfma_f32_16x16x32_f16(a, Bfrag[8 + kf], acc, 0, 0, 0);
        }

        // Activation per lane (gate type is uniform within a lane -> no divergence)
        floatx4 act;
        if (gate == 2) {
            #pragma unroll
            for (int e = 0; e < 4; ++e) act[e] = fast_tanh(acc[e]);
        } else {
            #pragma unroll
            for (int e = 0; e < 4; ++e) act[e] = fast_sigmoid(acc[e]);
        }

        // Gather i, c~, o into the f-lanes (cols jc, jc+4, jc+8, jc+12 share jc)
        float vi[4], vc[4], vo[4];
        #pragma unroll
        for (int e = 0; e < 4; ++e) {
            vi[e] = __shfl(act[e], l + 4);
            vc[e] = __shfl(act[e], l + 8);
            vo[e] = __shfl(act[e], l + 12);
        }

        if (gate == 0) {
            #pragma unroll
            for (int e = 0; e < 4; ++e) {
                float c = act[e] * cst[e] + vi[e] * vc[e];
                cst[e] = c;
                float h = vo[e] * fast_tanh(c);
                int b = row0 + (lk << 2) + e;      // C/D row = (l>>4)*4 + reg (m89)
                hwrite[(size_t)b * HSZ + hc] = (_Float16)h;
            }
        }

        grid.sync();
    }
}

__global__ void out_proj(const _Float16* __restrict__ h, const float* __restrict__ Wfc,
                         const float* __restrict__ bfc, float* __restrict__ out)
{
    int b = blockIdx.x;      // 64 blocks
    int l = threadIdx.x;     // 64 threads
    float s = 0.f;
    #pragma unroll
    for (int j = 0; j < 8; ++j) {
        int col = l + (j << 6);
        s += (float)h[(size_t)b * HSZ + col] * Wfc[col];
    }
    #pragma unroll
    for (int off = 32; off; off >>= 1) s += __shfl_down(s, off);
    if (l == 0) out[b] = s + bfc[0];
}

extern "C" void kernel_launch(void* const* d_in, const int* in_sizes, int n_in,
                              void* d_out, int out_size, void* d_ws, size_t ws_size,
                              hipStream_t stream)
{
    const float* x   = (const float*)d_in[0];
    const float* Wf  = (const float*)d_in[1];
    const float* bf  = (const float*)d_in[2];
    const float* Wi  = (const float*)d_in[3];
    const float* bi  = (const float*)d_in[4];
    const float* Wc  = (const float*)d_in[5];
    const float* bc  = (const float*)d_in[6];
    const float* Wo  = (const float*)d_in[7];
    const float* bo  = (const float*)d_in[8];
    const float* Wfc = (const float*)d_in[9];
    const float* bfc = (const float*)d_in[10];

    _Float16* hbuf = (_Float16*)d_ws;        // 2*64*512*2B = 128 KB
    float* out = (float*)d_out;

    // h_{-1} = 0 : zero both h buffers every launch (ws is not re-poisoned,
    // and we must be deterministic across replays).
    hipMemsetAsync(hbuf, 0, 2 * (size_t)BATCH * HSZ * sizeof(_Float16), stream);

    void* args[] = { (void*)&x, (void*)&Wf, (void*)&bf, (void*)&Wi, (void*)&bi,
                     (void*)&Wc, (void*)&bc, (void*)&Wo, (void*)&bo, (void*)&hbuf };
    hipLaunchCooperativeKernel((void*)lstm_persist, dim3(NWG), dim3(NTHR),
                               args, 0, stream);

    out_proj<<<dim3(BATCH), dim3(64), 0, stream>>>(hbuf, Wfc, bfc, out);
}

// Round 2
// 4736.230 us; speedup vs baseline: 4.4724x; 4.4724x over previous
//
#include <hip/hip_runtime.h>
#include <hip/hip_fp16.h>

// LSTM B=64, T=1024, I=256, H=512 — persistent weight-stationary.
// 128 WGs x 256 thr. WG g owns h-cols [4g,4g+4) = 16 gate cols; weight slice
// [768,16] f16 lives in registers (24 MFMA B-fragments). Per step each wave
// reads its 16 batch rows of h (agent-scope u64 atomic loads from L3 -- never
// cached in non-coherent L2), does 24 mfma_16x16x32_f16, activations, updates
// register c-state, shfl-transposes h to coalesced u64s, stores agent-scope,
// then arrives at a two-level monotonic counter barrier (16 group ctrs + root,
// relaxed atomics; release = asm s_waitcnt vmcnt(0) since all data ops are
// already L3-coherent). The x-part GEMM of step t+1 is computed after arrival,
// before the spin, hiding it under barrier latency.
//
// h layout: [2 bufs][128 col-blocks][64 rows][4 cols] f16 == u64[2][128][64].

#define T_STEPS 1024
#define BATCH   64
#define ISZ     256
#define HSZ     512
#define NWG     128
#define NTHR    256
#define HB4     ((BATCH * HSZ) / 4)   // u64 elems per h buffer (8192)

typedef _Float16 half8  __attribute__((ext_vector_type(8)));
typedef _Float16 half4  __attribute__((ext_vector_type(4)));
typedef float    floatx4 __attribute__((ext_vector_type(4)));
typedef unsigned long long u64;

#define LD_AGENT(p)     __hip_atomic_load((p), __ATOMIC_RELAXED, __HIP_MEMORY_SCOPE_AGENT)
#define ST_AGENT(p, v)  __hip_atomic_store((p), (v), __ATOMIC_RELAXED, __HIP_MEMORY_SCOPE_AGENT)
#define ADD_AGENT(p, v) __hip_atomic_fetch_add((p), (v), __ATOMIC_RELAXED, __HIP_MEMORY_SCOPE_AGENT)

__device__ __forceinline__ float fast_sigmoid(float x) {
    return 1.0f / (1.0f + __expf(-x));
}
__device__ __forceinline__ float fast_tanh(float x) {
    return 1.0f - 2.0f / (__expf(2.0f * x) + 1.0f);
}

__global__ __launch_bounds__(NTHR, 1) void lstm_persist(
    const float* __restrict__ x,
    const float* __restrict__ Wf, const float* __restrict__ bfv,
    const float* __restrict__ Wi, const float* __restrict__ biv,
    const float* __restrict__ Wc, const float* __restrict__ bcv,
    const float* __restrict__ Wo, const float* __restrict__ bov,
    u64* __restrict__ hbuf4, unsigned* __restrict__ ctrs)
{
    const int g    = blockIdx.x;        // 0..127
    const int tid  = threadIdx.x;
    const int w    = tid >> 6;          // wave 0..3 -> batch rows [16w,16w+16)
    const int l    = tid & 63;
    const int lj   = l & 15;
    const int lk   = l >> 4;
    const int gate = lj >> 2;           // 0=f 1=i 2=c~ 3=o
    const int jc   = lj & 3;
    const int hc   = (g << 2) + jc;     // h column
    const int row0 = w << 4;
    const int arow = row0 + lj;         // A-operand batch row
    const int grp  = g >> 3;            // 16 barrier groups of 8 WGs

    const float* Wg = (gate == 0) ? Wf : (gate == 1) ? Wi : (gate == 2) ? Wc : Wo;
    const float* bg = (gate == 0) ? bfv : (gate == 1) ? biv : (gate == 2) ? bcv : bov;

    // Weight fragments, resident for all 1024 steps. k within fragment =
    // kf*32 + lk*8 + e; A-fragments use the identical mapping.
    half8 Bfrag[24];
    #pragma unroll
    for (int kf = 0; kf < 24; ++kf) {
        half8 v;
        #pragma unroll
        for (int e = 0; e < 8; ++e) {
            int k = (kf << 5) + (lk << 3) + e;
            v[e] = (_Float16)Wg[(size_t)k * HSZ + hc];
        }
        Bfrag[kf] = v;
    }
    const float bias = bg[hc];
    float cst[4] = {0.f, 0.f, 0.f, 0.f};

    unsigned* lvl1 = &ctrs[grp * 16];   // 64B apart
    unsigned* root = &ctrs[16 * 16];

    // x-part MFMAs for t=0 (h_{-1}=0, so x-part + bias is the whole gate)
    floatx4 accx = {0.f, 0.f, 0.f, 0.f};
    {
        const float* xr = x + (size_t)arow * T_STEPS * ISZ + (lk << 3);
        #pragma unroll
        for (int kf = 0; kf < 8; ++kf) {
            floatx4 x0 = *(const floatx4*)(xr + (kf << 5));
            floatx4 x1 = *(const floatx4*)(xr + (kf << 5) + 4);
            half8 a;
            a[0] = (_Float16)x0[0]; a[1] = (_Float16)x0[1];
            a[2] = (_Float16)x0[2]; a[3] = (_Float16)x0[3];
            a[4] = (_Float16)x1[0]; a[5] = (_Float16)x1[1];
            a[6] = (_Float16)x1[2]; a[7] = (_Float16)x1[3];
            accx = __builtin_amdgcn_mfma_f32_16x16x32_f16(a, Bfrag[kf], accx, 0, 0, 0);
        }
    }

    for (int t = 0; t < T_STEPS; ++t) {
        floatx4 acc;
        #pragma unroll
        for (int e = 0; e < 4; ++e) acc[e] = accx[e] + bias;

        if (t > 0) {
            // wait for step t-1: root reaches 16*t (16 groups per step)
            if (tid == 0) {
                const unsigned tgt = 16u * (unsigned)t;
                while (LD_AGENT(root) < tgt) __builtin_amdgcn_s_sleep(1);
            }
            __syncthreads();

            const u64* hr = hbuf4 + (size_t)(t & 1) * HB4 + arow;
            u64 hl[32];
            #pragma unroll
            for (int kf = 0; kf < 16; ++kf) {
                const int c0 = kf * 8 + lk * 2;
                hl[2 * kf]     = LD_AGENT(hr + (size_t)c0 * BATCH);
                hl[2 * kf + 1] = LD_AGENT(hr + (size_t)(c0 + 1) * BATCH);
            }
            #pragma unroll
            for (int kf = 0; kf < 16; ++kf) {
                union { u64 u[2]; half8 h; } a;
                a.u[0] = hl[2 * kf];
                a.u[1] = hl[2 * kf + 1];
                acc = __builtin_amdgcn_mfma_f32_16x16x32_f16(a.h, Bfrag[8 + kf], acc, 0, 0, 0);
            }
        }

        // activations (gate uniform per lane)
        floatx4 act;
        if (gate == 2) {
            #pragma unroll
            for (int e = 0; e < 4; ++e) act[e] = fast_tanh(acc[e]);
        } else {
            #pragma unroll
            for (int e = 0; e < 4; ++e) act[e] = fast_sigmoid(acc[e]);
        }

        // broadcast all 4 gate values to every lane of the (lk,jc) quartet;
        // every lane keeps a replicated c-state -> h values
        const int base = l & ~12;
        float hv[4];
        #pragma unroll
        for (int e = 0; e < 4; ++e) {
            float vf = __shfl(act[e], base);
            float vi = __shfl(act[e], base + 4);
            float vc = __shfl(act[e], base + 8);
            float vo = __shfl(act[e], base + 12);
            float c  = vf * cst[e] + vi * vc;
            cst[e] = c;
            hv[e] = vo * fast_tanh(c);
        }

        // shfl-transpose: lane L<16 gathers row row0+L, cols 0..3 (packed u64)
        half4 outv;
        #pragma unroll
        for (int col = 0; col < 4; ++col) {
            const int src = ((l & 15) >> 2) * 16 + col;  // gate-0 lane, lk=L>>2, jc=col
            float sel = 0.f;
            #pragma unroll
            for (int e = 0; e < 4; ++e) {
                float tmp = __shfl(hv[e], src);
                if ((l & 3) == e) sel = tmp;             // element e = L&3
            }
            outv[col] = (_Float16)sel;
        }
        u64* hw = hbuf4 + (size_t)((t + 1) & 1) * HB4 + (size_t)g * BATCH + row0;
        if (l < 16) {
            union { half4 h; u64 u; } pk; pk.h = outv;
            ST_AGENT(hw + l, pk.u);
        }
        asm volatile("s_waitcnt vmcnt(0)" ::: "memory");   // h stores acked at L3
        __syncthreads();

        if (tid == 0) {
            unsigned old = ADD_AGENT(lvl1, 1u);
            if (old == 8u * (unsigned)(t + 1) - 1u)        // last of my group
                ADD_AGENT(root, 1u);
        }

        // hide x-part of step t+1 under other WGs' barrier progress
        if (t + 1 < T_STEPS) {
            floatx4 az = {0.f, 0.f, 0.f, 0.f};
            const float* xr = x + ((size_t)arow * T_STEPS + (t + 1)) * ISZ + (lk << 3);
            #pragma unroll
            for (int kf = 0; kf < 8; ++kf) {
                floatx4 x0 = *(const floatx4*)(xr + (kf << 5));
                floatx4 x1 = *(const floatx4*)(xr + (kf << 5) + 4);
                half8 a;
                a[0] = (_Float16)x0[0]; a[1] = (_Float16)x0[1];
                a[2] = (_Float16)x0[2]; a[3] = (_Float16)x0[3];
                a[4] = (_Float16)x1[0]; a[5] = (_Float16)x1[1];
                a[6] = (_Float16)x1[2]; a[7] = (_Float16)x1[3];
                az = __builtin_amdgcn_mfma_f32_16x16x32_f16(a, Bfrag[kf], az, 0, 0, 0);
            }
            accx = az;
        }
    }
}

// final h is in hbuf4[0] (t=1023 writes buffer (1023+1)&1 = 0)
__global__ void out_proj(const u64* __restrict__ hb4, const float* __restrict__ Wfc,
                         const float* __restrict__ bfc, float* __restrict__ out)
{
    const int b = blockIdx.x;      // 64
    const int l = threadIdx.x;     // 64
    float s = 0.f;
    #pragma unroll
    for (int j = 0; j < 2; ++j) {
        const int c4 = l + (j << 6);              // col block 0..127
        union { u64 u; half4 h; } v;
        v.u = hb4[(size_t)c4 * BATCH + b];
        #pragma unroll
        for (int q = 0; q < 4; ++q)
            s += (float)v.h[q] * Wfc[c4 * 4 + q];
    }
    #pragma unroll
    for (int off = 32; off; off >>= 1) s += __shfl_down(s, off);
    if (l == 0) out[b] = s + bfc[0];
}

extern "C" void kernel_launch(void* const* d_in, const int* in_sizes, int n_in,
                              void* d_out, int out_size, void* d_ws, size_t ws_size,
                              hipStream_t stream)
{
    const float* x   = (const float*)d_in[0];
    const float* Wf  = (const float*)d_in[1];
    const float* bf  = (const float*)d_in[2];
    const float* Wi  = (const float*)d_in[3];
    const float* bi  = (const float*)d_in[4];
    const float* Wc  = (const float*)d_in[5];
    const float* bc  = (const float*)d_in[6];
    const float* Wo  = (const float*)d_in[7];
    const float* bo  = (const float*)d_in[8];
    const float* Wfc = (const float*)d_in[9];
    const float* bfc = (const float*)d_in[10];

    u64* hbuf4 = (u64*)d_ws;                                   // 2*8192*8 = 128 KB
    unsigned* ctrs = (unsigned*)((char*)d_ws + 2 * HB4 * sizeof(u64));
    float* out = (float*)d_out;

    // counters must restart at 0 every launch (monotonic targets)
    hipMemsetAsync(ctrs, 0, 2048, stream);

    void* args[] = { (void*)&x, (void*)&Wf, (void*)&bf, (void*)&Wi, (void*)&bi,
                     (void*)&Wc, (void*)&bc, (void*)&Wo, (void*)&bo,
                     (void*)&hbuf4, (void*)&ctrs };
    hipLaunchCooperativeKernel((void*)lstm_persist, dim3(NWG), dim3(NTHR),
                               args, 0, stream);

    out_proj<<<dim3(BATCH), dim3(64), 0, stream>>>(hbuf4, Wfc, bfc, (float*)d_out);
}

// Round 3
// 4457.150 us; speedup vs baseline: 4.7524x; 1.0626x over previous
//
#include <hip/hip_runtime.h>
#include <hip/hip_fp16.h>

// LSTM B=64, T=1024, I=256, H=512 — persistent weight-stationary, wave-autonomous.
//
// 128 WGs x 256 thr. Wave w of WG g owns: batch rows [16w,16w+16) x gate cols
// for h-cols [4g,4g+4). Weight slice [768,16] f16 in registers (24 B-frags).
// Per step: read h rows [16w,16w+16) (agent-scope u64 loads, L3-coherent),
// 16 h-MFMAs (two 8-deep chains) + 8 x-MFMAs (precomputed, hidden under spin),
// activations, register c-state update, shfl-transpose, 16 coalesced u64
// agent stores, vmcnt(0), then ONE relaxed store to this wave's own 64B-padded
// counter. Readers poll 128 counters of their row-block with 2 loads/lane +
// __all — no atomics RMW, no __syncthreads, no cross-row-block coupling.
// Double-buffer safety: ctr[w][g]=t+1 implies that wave finished step-t reads
// (vmcnt(0) drains loads+stores), so overwriting buf[t&1] at step t+1 is safe.
//
// h layout: [2][128 col-blocks][64 rows] u64, u64 = 4 consecutive cols f16.

#define T_STEPS 1024
#define BATCH   64
#define ISZ     256
#define HSZ     512
#define NWG     128
#define NTHR    256
#define HB4     ((BATCH * HSZ) / 4)   // u64 per h buffer (8192)
#define CTR_STRIDE 16                 // u32s -> 64B padding

typedef _Float16 half8  __attribute__((ext_vector_type(8)));
typedef _Float16 half4  __attribute__((ext_vector_type(4)));
typedef float    floatx4 __attribute__((ext_vector_type(4)));
typedef unsigned long long u64;

#define LD_AGENT(p)     __hip_atomic_load((p), __ATOMIC_RELAXED, __HIP_MEMORY_SCOPE_AGENT)
#define ST_AGENT(p, v)  __hip_atomic_store((p), (v), __ATOMIC_RELAXED, __HIP_MEMORY_SCOPE_AGENT)

__device__ __forceinline__ float fast_sigmoid(float x) {
    return 1.0f / (1.0f + __expf(-x));
}
__device__ __forceinline__ float fast_tanh(float x) {
    return 1.0f - 2.0f / (__expf(2.0f * x) + 1.0f);
}

__global__ __launch_bounds__(NTHR, 1) void lstm_persist(
    const float* __restrict__ x,
    const float* __restrict__ Wf, const float* __restrict__ bfv,
    const float* __restrict__ Wi, const float* __restrict__ biv,
    const float* __restrict__ Wc, const float* __restrict__ bcv,
    const float* __restrict__ Wo, const float* __restrict__ bov,
    u64* __restrict__ hbuf4, unsigned* __restrict__ ctrs)
{
    const int g    = blockIdx.x;        // 0..127
    const int tid  = threadIdx.x;
    const int w    = tid >> 6;          // wave -> row-block [16w,16w+16)
    const int l    = tid & 63;
    const int lj   = l & 15;
    const int lk   = l >> 4;
    const int gate = lj >> 2;           // 0=f 1=i 2=c~ 3=o
    const int jc   = lj & 3;
    const int hc   = (g << 2) + jc;     // h column
    const int row0 = w << 4;
    const int arow = row0 + lj;         // A-operand batch row

    const float* Wg = (gate == 0) ? Wf : (gate == 1) ? Wi : (gate == 2) ? Wc : Wo;
    const float* bg = (gate == 0) ? bfv : (gate == 1) ? biv : (gate == 2) ? bcv : bov;

    // Weight fragments, resident for all 1024 steps. k in fragment =
    // kf*32 + lk*8 + e; A-fragments use the identical k mapping.
    half8 Bfrag[24];
    #pragma unroll
    for (int kf = 0; kf < 24; ++kf) {
        half8 v;
        #pragma unroll
        for (int e = 0; e < 8; ++e) {
            int k = (kf << 5) + (lk << 3) + e;
            v[e] = (_Float16)Wg[(size_t)k * HSZ + hc];
        }
        Bfrag[kf] = v;
    }
    const float bias = bg[hc];
    float cst[4] = {0.f, 0.f, 0.f, 0.f};

    // per-wave counter (64B padded); row-block w polls its 128 counters
    unsigned* myctr = ctrs + ((size_t)w * NWG + g) * CTR_STRIDE;
    const unsigned* cb = ctrs + (size_t)w * NWG * CTR_STRIDE;
    const unsigned* cA = cb + (size_t)l * CTR_STRIDE;
    const unsigned* cB = cb + (size_t)(l + 64) * CTR_STRIDE;

    // x-part for t=0
    floatx4 accx = {0.f, 0.f, 0.f, 0.f};
    {
        const float* xr = x + (size_t)arow * T_STEPS * ISZ + (lk << 3);
        #pragma unroll
        for (int kf = 0; kf < 8; ++kf) {
            floatx4 x0 = *(const floatx4*)(xr + (kf << 5));
            floatx4 x1 = *(const floatx4*)(xr + (kf << 5) + 4);
            half8 a;
            a[0] = (_Float16)x0[0]; a[1] = (_Float16)x0[1];
            a[2] = (_Float16)x0[2]; a[3] = (_Float16)x0[3];
            a[4] = (_Float16)x1[0]; a[5] = (_Float16)x1[1];
            a[6] = (_Float16)x1[2]; a[7] = (_Float16)x1[3];
            accx = __builtin_amdgcn_mfma_f32_16x16x32_f16(a, Bfrag[kf], accx, 0, 0, 0);
        }
    }

    for (int t = 0; t < T_STEPS; ++t) {
        floatx4 acc0, acc1;
        #pragma unroll
        for (int e = 0; e < 4; ++e) { acc0[e] = accx[e] + bias; acc1[e] = 0.f; }

        if (t > 0) {
            // wait: all 128 waves of row-block w finished step t-1
            const unsigned tgt = (unsigned)t;
            while (true) {
                unsigned a = LD_AGENT(cA);
                unsigned b = LD_AGENT(cB);
                if (__all((a >= tgt) && (b >= tgt))) break;
                __builtin_amdgcn_s_sleep(1);
            }

            const u64* hr = hbuf4 + (size_t)(t & 1) * HB4 + arow;
            u64 hl[32];
            #pragma unroll
            for (int kf = 0; kf < 16; ++kf) {
                const int c0 = kf * 8 + lk * 2;
                hl[2 * kf]     = LD_AGENT(hr + (size_t)c0 * BATCH);
                hl[2 * kf + 1] = LD_AGENT(hr + (size_t)(c0 + 1) * BATCH);
            }
            // two independent 8-deep MFMA chains
            #pragma unroll
            for (int kf = 0; kf < 16; kf += 2) {
                union { u64 u[2]; half8 h; } a0, a1;
                a0.u[0] = hl[2 * kf];     a0.u[1] = hl[2 * kf + 1];
                a1.u[0] = hl[2 * kf + 2]; a1.u[1] = hl[2 * kf + 3];
                acc0 = __builtin_amdgcn_mfma_f32_16x16x32_f16(a0.h, Bfrag[8 + kf], acc0, 0, 0, 0);
                acc1 = __builtin_amdgcn_mfma_f32_16x16x32_f16(a1.h, Bfrag[9 + kf], acc1, 0, 0, 0);
            }
        }

        // activations (gate uniform per lane)
        floatx4 act;
        if (gate == 2) {
            #pragma unroll
            for (int e = 0; e < 4; ++e) act[e] = fast_tanh(acc0[e] + acc1[e]);
        } else {
            #pragma unroll
            for (int e = 0; e < 4; ++e) act[e] = fast_sigmoid(acc0[e] + acc1[e]);
        }

        // broadcast 4 gate values within each (lk,jc) quartet; replicated c-state
        const int base = l & ~12;
        float hv[4];
        #pragma unroll
        for (int e = 0; e < 4; ++e) {
            float vf = __shfl(act[e], base);
            float vi = __shfl(act[e], base + 4);
            float vc = __shfl(act[e], base + 8);
            float vo = __shfl(act[e], base + 12);
            float c  = vf * cst[e] + vi * vc;
            cst[e] = c;
            hv[e] = vo * fast_tanh(c);
        }

        // shfl-transpose: lane L<16 gathers row row0+L, cols 4g..4g+4 (u64)
        half4 outv;
        #pragma unroll
        for (int col = 0; col < 4; ++col) {
            const int src = ((l & 15) >> 2) * 16 + col;
            float sel = 0.f;
            #pragma unroll
            for (int e = 0; e < 4; ++e) {
                float tmp = __shfl(hv[e], src);
                if ((l & 3) == e) sel = tmp;
            }
            outv[col] = (_Float16)sel;
        }
        u64* hw = hbuf4 + (size_t)((t + 1) & 1) * HB4 + (size_t)g * BATCH + row0;
        if (l < 16) {
            union { half4 h; u64 u; } pk; pk.h = outv;
            ST_AGENT(hw + l, pk.u);
        }
        asm volatile("s_waitcnt vmcnt(0)" ::: "memory");   // h stores at L3
        if (l == 0) ST_AGENT(myctr, (unsigned)(t + 1));    // single plain arrival store

        // x-part of step t+1, hidden under other waves' progress + our spin
        if (t + 1 < T_STEPS) {
            floatx4 az = {0.f, 0.f, 0.f, 0.f};
            const float* xr = x + ((size_t)arow * T_STEPS + (t + 1)) * ISZ + (lk << 3);
            #pragma unroll
            for (int kf = 0; kf < 8; ++kf) {
                floatx4 x0 = *(const floatx4*)(xr + (kf << 5));
                floatx4 x1 = *(const floatx4*)(xr + (kf << 5) + 4);
                half8 a;
                a[0] = (_Float16)x0[0]; a[1] = (_Float16)x0[1];
                a[2] = (_Float16)x0[2]; a[3] = (_Float16)x0[3];
                a[4] = (_Float16)x1[0]; a[5] = (_Float16)x1[1];
                a[6] = (_Float16)x1[2]; a[7] = (_Float16)x1[3];
                az = __builtin_amdgcn_mfma_f32_16x16x32_f16(a, Bfrag[kf], az, 0, 0, 0);
            }
            accx = az;
        }
    }
}

// final h is in hbuf4[0] (t=1023 writes buffer (1023+1)&1 = 0)
__global__ void out_proj(const u64* __restrict__ hb4, const float* __restrict__ Wfc,
                         const float* __restrict__ bfc, float* __restrict__ out)
{
    const int b = blockIdx.x;      // 64
    const int l = threadIdx.x;     // 64
    float s = 0.f;
    #pragma unroll
    for (int j = 0; j < 2; ++j) {
        const int c4 = l + (j << 6);
        union { u64 u; half4 h; } v;
        v.u = hb4[(size_t)c4 * BATCH + b];
        #pragma unroll
        for (int q = 0; q < 4; ++q)
            s += (float)v.h[q] * Wfc[c4 * 4 + q];
    }
    #pragma unroll
    for (int off = 32; off; off >>= 1) s += __shfl_down(s, off);
    if (l == 0) out[b] = s + bfc[0];
}

extern "C" void kernel_launch(void* const* d_in, const int* in_sizes, int n_in,
                              void* d_out, int out_size, void* d_ws, size_t ws_size,
                              hipStream_t stream)
{
    const float* x   = (const float*)d_in[0];
    const float* Wf  = (const float*)d_in[1];
    const float* bf  = (const float*)d_in[2];
    const float* Wi  = (const float*)d_in[3];
    const float* bi  = (const float*)d_in[4];
    const float* Wc  = (const float*)d_in[5];
    const float* bc  = (const float*)d_in[6];
    const float* Wo  = (const float*)d_in[7];
    const float* bo  = (const float*)d_in[8];
    const float* Wfc = (const float*)d_in[9];
    const float* bfc = (const float*)d_in[10];

    u64* hbuf4 = (u64*)d_ws;                                   // 128 KB
    unsigned* ctrs = (unsigned*)((char*)d_ws + 2 * HB4 * sizeof(u64));  // 32 KB

    // counters restart at 0 every launch (monotonic targets, graph-replay safe)
    hipMemsetAsync(ctrs, 0, 4 * NWG * CTR_STRIDE * sizeof(unsigned), stream);

    void* args[] = { (void*)&x, (void*)&Wf, (void*)&bf, (void*)&Wi, (void*)&bi,
                     (void*)&Wc, (void*)&bc, (void*)&Wo, (void*)&bo,
                     (void*)&hbuf4, (void*)&ctrs };
    hipLaunchCooperativeKernel((void*)lstm_persist, dim3(NWG), dim3(NTHR),
                               args, 0, stream);

    out_proj<<<dim3(BATCH), dim3(64), 0, stream>>>(hbuf4, Wfc, bfc, (float*)d_out);
}